// Round 1
// baseline (2593.282 us; speedup 1.0000x reference)
//
#include <hip/hip_runtime.h>

#define NB   8
#define CIN  1024
#define TT   4096
#define DVQ  1024
#define KC   2048
#define TH   2048
#define MM   (NB * TH)   // 16384

// ---------------------------------------------------------------- cnorm ----
__global__ __launch_bounds__(256) void k_cnorm(const float* __restrict__ cb,
                                               float* __restrict__ cnorm) {
    __shared__ float red[256];
    int k = blockIdx.x;
    const float* row = cb + (size_t)k * DVQ;
    float4 v = *reinterpret_cast<const float4*>(row + threadIdx.x * 4);
    float s = v.x * v.x + v.y * v.y + v.z * v.z + v.w * v.w;
    red[threadIdx.x] = s;
    __syncthreads();
    for (int o = 128; o > 0; o >>= 1) {
        if (threadIdx.x < o) red[threadIdx.x] += red[threadIdx.x + o];
        __syncthreads();
    }
    if (threadIdx.x == 0) cnorm[k] = red[0];
}

// ------------------------------------------------------- conv_in as GEMM ---
// xt[m][n] = sum_k A[m][k] * W[n][k],  A[m][(i,s)] = x[b, i, 2t+s]
__global__ __launch_bounds__(256) void k_conv_in(const float* __restrict__ x,
                                                 const float* __restrict__ w,
                                                 const float* __restrict__ bias,
                                                 float* __restrict__ xt) {
    __shared__ float As[16][64];
    __shared__ float Bs[16][64];
    const int tid = threadIdx.x;
    const int tx = tid & 15, ty = tid >> 4;
    const int m0 = blockIdx.x * 64;
    const int n0 = blockIdx.y * 64;
    const int b  = m0 >> 11;          // 2048 t per batch, block never straddles b
    const int t0 = m0 & 2047;
    const float* xb = x + (size_t)b * CIN * TT;

    float acc[4][4] = {};
    const int im2a = tid & 63, ih2a = tid >> 6;          // A-load lane mapping (j=0)
    const int inB = tid >> 2, qqB = (tid & 3) * 4;       // B-load lane mapping

    for (int k0 = 0; k0 < 2048; k0 += 16) {
        const int i0 = k0 >> 1;
        // global loads into registers first (overlap with prior compute)
        float2 a0 = *reinterpret_cast<const float2*>(xb + (size_t)(i0 + ih2a) * TT + 2 * (t0 + im2a));
        float2 a1 = *reinterpret_cast<const float2*>(xb + (size_t)(i0 + ih2a + 4) * TT + 2 * (t0 + im2a));
        float4 bw = *reinterpret_cast<const float4*>(w + (size_t)(n0 + inB) * 2048 + k0 + qqB);
        __syncthreads();   // prior tile compute done
        As[ih2a * 2 + 0][im2a] = a0.x;
        As[ih2a * 2 + 1][im2a] = a0.y;
        As[(ih2a + 4) * 2 + 0][im2a] = a1.x;
        As[(ih2a + 4) * 2 + 1][im2a] = a1.y;
        Bs[qqB + 0][inB] = bw.x;
        Bs[qqB + 1][inB] = bw.y;
        Bs[qqB + 2][inB] = bw.z;
        Bs[qqB + 3][inB] = bw.w;
        __syncthreads();
#pragma unroll
        for (int kk = 0; kk < 16; ++kk) {
            const float4 a = *reinterpret_cast<const float4*>(&As[kk][ty * 4]);
            const float4 b4 = *reinterpret_cast<const float4*>(&Bs[kk][tx * 4]);
            const float av[4] = {a.x, a.y, a.z, a.w};
            const float bv[4] = {b4.x, b4.y, b4.z, b4.w};
#pragma unroll
            for (int r = 0; r < 4; ++r)
#pragma unroll
                for (int j = 0; j < 4; ++j) acc[r][j] += av[r] * bv[j];
        }
    }
#pragma unroll
    for (int r = 0; r < 4; ++r) {
        const int m = m0 + ty * 4 + r;
        float4 v;
        v.x = acc[r][0] + bias[n0 + tx * 4 + 0];
        v.y = acc[r][1] + bias[n0 + tx * 4 + 1];
        v.z = acc[r][2] + bias[n0 + tx * 4 + 2];
        v.w = acc[r][3] + bias[n0 + tx * 4 + 3];
        *reinterpret_cast<float4*>(xt + (size_t)m * DVQ + n0 + tx * 4) = v;
    }
}

// --------------------------------------------- distances + partial argmin --
// score[m][k] = cnorm[k] - 2 * dot(xt[m], cb[k]); each block covers 512 codewords
__global__ __launch_bounds__(256) void k_argmin(const float* __restrict__ xt,
                                                const float* __restrict__ cb,
                                                const float* __restrict__ cnorm,
                                                float* __restrict__ pbv,
                                                int* __restrict__ pbk) {
    __shared__ float As[16][64];
    __shared__ float Bs[16][64];
    __shared__ float cns[64];
    __shared__ float rv[64][16];
    __shared__ int   rk[64][16];
    const int tid = threadIdx.x;
    const int tx = tid & 15, ty = tid >> 4;
    const int m0 = blockIdx.x * 64;
    const int nbase = blockIdx.y * 512;
    const int im = tid >> 2, kq = (tid & 3) * 4;

    float bestv[4] = {INFINITY, INFINITY, INFINITY, INFINITY};
    int bestk[4] = {0, 0, 0, 0};

    for (int c = 0; c < 8; ++c) {
        const int n0 = nbase + c * 64;
        if (tid < 64) cns[tid] = cnorm[n0 + tid];
        float acc[4][4] = {};
        for (int k0 = 0; k0 < DVQ; k0 += 16) {
            float4 ga = *reinterpret_cast<const float4*>(xt + (size_t)(m0 + im) * DVQ + k0 + kq);
            float4 gb = *reinterpret_cast<const float4*>(cb + (size_t)(n0 + im) * DVQ + k0 + kq);
            __syncthreads();
            As[kq + 0][im] = ga.x; As[kq + 1][im] = ga.y; As[kq + 2][im] = ga.z; As[kq + 3][im] = ga.w;
            Bs[kq + 0][im] = gb.x; Bs[kq + 1][im] = gb.y; Bs[kq + 2][im] = gb.z; Bs[kq + 3][im] = gb.w;
            __syncthreads();
#pragma unroll
            for (int kk = 0; kk < 16; ++kk) {
                const float4 a = *reinterpret_cast<const float4*>(&As[kk][ty * 4]);
                const float4 b4 = *reinterpret_cast<const float4*>(&Bs[kk][tx * 4]);
                const float av[4] = {a.x, a.y, a.z, a.w};
                const float bv[4] = {b4.x, b4.y, b4.z, b4.w};
#pragma unroll
                for (int r = 0; r < 4; ++r)
#pragma unroll
                    for (int j = 0; j < 4; ++j) acc[r][j] += av[r] * bv[j];
            }
        }
        // ascending-k scan with strict < keeps the first occurrence (np.argmin)
#pragma unroll
        for (int r = 0; r < 4; ++r)
#pragma unroll
            for (int j = 0; j < 4; ++j) {
                const float sc = cns[tx * 4 + j] - 2.0f * acc[r][j];
                const int ki = n0 + tx * 4 + j;
                if (sc < bestv[r]) { bestv[r] = sc; bestk[r] = ki; }
            }
        __syncthreads();   // cns reused next chunk
    }
#pragma unroll
    for (int r = 0; r < 4; ++r) { rv[ty * 4 + r][tx] = bestv[r]; rk[ty * 4 + r][tx] = bestk[r]; }
    __syncthreads();
    if (tid < 64) {
        float bv = rv[tid][0]; int bk = rk[tid][0];
        for (int j = 1; j < 16; ++j) {
            const float v = rv[tid][j]; const int kk2 = rk[tid][j];
            if (v < bv || (v == bv && kk2 < bk)) { bv = v; bk = kk2; }
        }
        pbv[(size_t)blockIdx.y * MM + m0 + tid] = bv;
        pbk[(size_t)blockIdx.y * MM + m0 + tid] = bk;
    }
}

__global__ __launch_bounds__(256) void k_argmin2(const float* __restrict__ pbv,
                                                 const int* __restrict__ pbk,
                                                 int* __restrict__ idxbuf,
                                                 float* __restrict__ idx_out) {
    const int m = blockIdx.x * 256 + threadIdx.x;
    float bv = pbv[m]; int bk = pbk[m];
#pragma unroll
    for (int y = 1; y < 4; ++y) {
        const float v = pbv[(size_t)y * MM + m]; const int k = pbk[(size_t)y * MM + m];
        if (v < bv || (v == bv && k < bk)) { bv = v; bk = k; }
    }
    idxbuf[m] = bk;
    idx_out[m] = (float)bk;
}

// -------------------------------------------------------------- loss -------
__global__ __launch_bounds__(256) void k_losspart(const float* __restrict__ xt,
                                                  const float* __restrict__ cb,
                                                  const int* __restrict__ idxbuf,
                                                  float* __restrict__ partials) {
    __shared__ float red[256];
    const int m = blockIdx.x;
    const int row = idxbuf[m];
    float4 a = reinterpret_cast<const float4*>(xt + (size_t)m * DVQ)[threadIdx.x];
    float4 c = reinterpret_cast<const float4*>(cb + (size_t)row * DVQ)[threadIdx.x];
    const float dx = a.x - c.x, dy = a.y - c.y, dz = a.z - c.z, dw = a.w - c.w;
    red[threadIdx.x] = dx * dx + dy * dy + dz * dz + dw * dw;
    __syncthreads();
    for (int o = 128; o > 0; o >>= 1) {
        if (threadIdx.x < o) red[threadIdx.x] += red[threadIdx.x + o];
        __syncthreads();
    }
    if (threadIdx.x == 0) partials[m] = red[0];
}

__global__ __launch_bounds__(256) void k_lossfinal(const float* __restrict__ partials,
                                                   float* __restrict__ loss_out) {
    __shared__ float red[256];
    float s = 0.0f;
    for (int i = threadIdx.x; i < MM; i += 256) s += partials[i];
    red[threadIdx.x] = s;
    __syncthreads();
    for (int o = 128; o > 0; o >>= 1) {
        if (threadIdx.x < o) red[threadIdx.x] += red[threadIdx.x + o];
        __syncthreads();
    }
    if (threadIdx.x == 0) loss_out[0] = red[0] / (float)((size_t)MM * DVQ);
}

// --------------------------------------------------- out projection GEMM ---
// out[b][n][2t+s] = mask * (sum_d cb[idx[m]][d] * w2[n][d] + bias[n])
__global__ __launch_bounds__(256) void k_out(const int* __restrict__ idxbuf,
                                             const float* __restrict__ cb,
                                             const float* __restrict__ w2,
                                             const float* __restrict__ bias,
                                             const float* __restrict__ xmask,
                                             float* __restrict__ out) {
    __shared__ float As[16][64];
    __shared__ float Bs[16][64];
    __shared__ int rows[64];
    const int tid = threadIdx.x;
    const int tx = tid & 15, ty = tid >> 4;
    const int m0 = blockIdx.x * 64;
    const int n0 = blockIdx.y * 64;
    if (tid < 64) rows[tid] = idxbuf[m0 + tid];
    __syncthreads();
    const int im = tid >> 2, kq = (tid & 3) * 4;

    float acc[4][4] = {};
    for (int k0 = 0; k0 < DVQ; k0 += 16) {
        float4 ga = *reinterpret_cast<const float4*>(cb + (size_t)rows[im] * DVQ + k0 + kq);
        float4 gb = *reinterpret_cast<const float4*>(w2 + (size_t)(n0 + im) * DVQ + k0 + kq);
        __syncthreads();
        As[kq + 0][im] = ga.x; As[kq + 1][im] = ga.y; As[kq + 2][im] = ga.z; As[kq + 3][im] = ga.w;
        Bs[kq + 0][im] = gb.x; Bs[kq + 1][im] = gb.y; Bs[kq + 2][im] = gb.z; Bs[kq + 3][im] = gb.w;
        __syncthreads();
#pragma unroll
        for (int kk = 0; kk < 16; ++kk) {
            const float4 a = *reinterpret_cast<const float4*>(&As[kk][ty * 4]);
            const float4 b4 = *reinterpret_cast<const float4*>(&Bs[kk][tx * 4]);
            const float av[4] = {a.x, a.y, a.z, a.w};
            const float bv[4] = {b4.x, b4.y, b4.z, b4.w};
#pragma unroll
            for (int r = 0; r < 4; ++r)
#pragma unroll
                for (int j = 0; j < 4; ++j) acc[r][j] += av[r] * bv[j];
        }
    }
#pragma unroll
    for (int r = 0; r < 4; ++r) {
        const int m = m0 + ty * 4 + r;
        const int b = m >> 11, t = m & 2047;
        const float mk0 = xmask[(size_t)b * TT + 2 * t];
        const float mk1 = xmask[(size_t)b * TT + 2 * t + 1];
        const size_t ob = (size_t)b * CIN * TT + 2 * t;
#pragma unroll
        for (int j = 0; j < 4; ++j) {
            const int n = n0 + tx * 4 + j;
            const float v = acc[r][j] + bias[n];
            float2 o2; o2.x = v * mk0; o2.y = v * mk1;
            *reinterpret_cast<float2*>(out + ob + (size_t)n * TT) = o2;
        }
    }
}

// ---------------------------------------------------------------- launch ---
extern "C" void kernel_launch(void* const* d_in, const int* in_sizes, int n_in,
                              void* d_out, int out_size, void* d_ws, size_t ws_size,
                              hipStream_t stream) {
    const float* x  = (const float*)d_in[0];
    const float* xm = (const float*)d_in[1];
    const float* wi = (const float*)d_in[2];
    const float* bi = (const float*)d_in[3];
    const float* cb = (const float*)d_in[4];
    const float* wo = (const float*)d_in[5];
    const float* bo = (const float*)d_in[6];

    float* outp     = (float*)d_out;
    float* idx_out  = outp + (size_t)NB * CIN * TT;   // 33,554,432
    float* loss_out = idx_out + MM;                   // +16,384

    char* ws = (char*)d_ws;
    float* xt       = (float*)ws;                                   // 64 MB
    float* cnorm    = (float*)(ws + (size_t)MM * DVQ * 4);          // 8 KB
    float* partials = cnorm + KC;                                   // 64 KB
    int*   idxbuf   = (int*)(partials + MM);                        // 64 KB
    float* pbv      = (float*)(idxbuf + MM);                        // 256 KB
    int*   pbk      = (int*)(pbv + 4 * MM);                         // 256 KB

    dim3 blk(256);
    k_cnorm   <<<dim3(KC), blk, 0, stream>>>(cb, cnorm);
    k_conv_in <<<dim3(MM / 64, DVQ / 64), blk, 0, stream>>>(x, wi, bi, xt);
    k_argmin  <<<dim3(MM / 64, 4), blk, 0, stream>>>(xt, cb, cnorm, pbv, pbk);
    k_argmin2 <<<dim3(MM / 256), blk, 0, stream>>>(pbv, pbk, idxbuf, idx_out);
    k_losspart<<<dim3(MM), blk, 0, stream>>>(xt, cb, idxbuf, partials);
    k_lossfinal<<<1, blk, 0, stream>>>(partials, loss_out);
    k_out     <<<dim3(MM / 64, CIN / 64), blk, 0, stream>>>(idxbuf, cb, wo, bo, xm, outp);
}

// Round 4
// 1145.332 us; speedup vs baseline: 2.2642x; 2.2642x over previous
//
#include <hip/hip_runtime.h>

#define NB   8
#define CIN  1024
#define TT   4096
#define DVQ  1024
#define KC   2048
#define MM   16384

typedef short s16x8 __attribute__((ext_vector_type(8)));
typedef float f32x4 __attribute__((ext_vector_type(4)));

__device__ __forceinline__ short f2bf(float f) {
    unsigned u = __float_as_uint(f);
    u = u + 0x7fffu + ((u >> 16) & 1u);   // RNE
    return (short)(u >> 16);
}
__device__ __forceinline__ float bf2f(short h) {
    return __uint_as_float(((unsigned)(unsigned short)h) << 16);
}
__device__ __forceinline__ unsigned pk(short a, short b) {
    return (unsigned)(unsigned short)a | ((unsigned)(unsigned short)b << 16);
}
__device__ __forceinline__ void split3(float v, short& h, short& m, short& l) {
    h = f2bf(v); float r1 = v - bf2f(h);
    m = f2bf(r1); float r2 = r1 - bf2f(m);
    l = f2bf(r2);
}
// swizzled A-plane address (shorts): row-major, 40 shorts/row, 8-short blocks
// XOR-permuted by (row>>3)&3.
__device__ __forceinline__ int aswz(int row, int q) {
    return row * 40 + (((q ^ (row >> 3)) & 3) << 3);
}
__device__ __forceinline__ bool lesskey(float v, int k, float v2, int k2) {
    return v < v2 || (v == v2 && k < k2);
}
__device__ __forceinline__ void merge2(float& b1, int& k1, float& b2, int& k2,
                                       float o1, int ok1, float o2, int ok2) {
    if (lesskey(o1, ok1, b1, k1)) {
        float nb2; int nk2;
        if (lesskey(b1, k1, o2, ok2)) { nb2 = b1; nk2 = k1; } else { nb2 = o2; nk2 = ok2; }
        b1 = o1; k1 = ok1; b2 = nb2; k2 = nk2;
    } else if (lesskey(o1, ok1, b2, k2)) {
        b2 = o1; k2 = ok1;
    }
}

// ============================= preps =======================================
__global__ __launch_bounds__(256) void k_split3(const float* __restrict__ src,
                                                short* __restrict__ h, short* __restrict__ m,
                                                short* __restrict__ l, int n4) {
    int i = blockIdx.x * 256 + threadIdx.x;
    if (i >= n4) return;
    float4 v = ((const float4*)src)[i];
    short4 H, M, L;
    split3(v.x, H.x, M.x, L.x); split3(v.y, H.y, M.y, L.y);
    split3(v.z, H.z, M.z, L.z); split3(v.w, H.w, M.w, L.w);
    ((short4*)h)[i] = H; ((short4*)m)[i] = M; ((short4*)l)[i] = L;
}

__global__ __launch_bounds__(256) void k_split2(const float* __restrict__ src,
                                                short* __restrict__ h, short* __restrict__ l, int n4) {
    int i = blockIdx.x * 256 + threadIdx.x;
    if (i >= n4) return;
    float4 v = ((const float4*)src)[i];
    short4 H, L;
    H.x = f2bf(v.x); L.x = f2bf(v.x - bf2f(H.x));
    H.y = f2bf(v.y); L.y = f2bf(v.y - bf2f(H.y));
    H.z = f2bf(v.z); L.z = f2bf(v.z - bf2f(H.z));
    H.w = f2bf(v.w); L.w = f2bf(v.w - bf2f(H.w));
    ((short4*)h)[i] = H; ((short4*)l)[i] = L;
}

__global__ __launch_bounds__(256) void k_cnorm(const float* __restrict__ cb,
                                               float* __restrict__ c32,
                                               double* __restrict__ c64) {
    __shared__ double red[256];
    const float* row = cb + (size_t)blockIdx.x * DVQ;
    float4 v = ((const float4*)row)[threadIdx.x];
    red[threadIdx.x] = (double)v.x * v.x + (double)v.y * v.y +
                       (double)v.z * v.z + (double)v.w * v.w;
    __syncthreads();
    for (int o = 128; o > 0; o >>= 1) {
        if (threadIdx.x < o) red[threadIdx.x] += red[threadIdx.x + o];
        __syncthreads();
    }
    if (threadIdx.x == 0) { c64[blockIdx.x] = red[0]; c32[blockIdx.x] = (float)red[0]; }
}

// ======== conv-in GEMM: 3-plane bf16, 6 products, chunked accumulation =====
// Tile 128(M)x64(N), BK=32, 4 waves (2x2), wave tile 64x32.
// Accumulators flushed to f32 sums every 2 K-iterations (chunk K=64) to kill
// the f32 random-walk rounding (per-elem xt error ~3e-7 vs ~2e-6 unchunked).
__global__ __launch_bounds__(256, 2) void k_conv(const float* __restrict__ x,
                                                 const short* __restrict__ wh,
                                                 const short* __restrict__ wm,
                                                 const short* __restrict__ wl,
                                                 const float* __restrict__ bias,
                                                 float* __restrict__ xt,
                                                 short* __restrict__ xth,
                                                 short* __restrict__ xtl) {
    __shared__ short sAh[128 * 40], sAm[128 * 40], sAl[128 * 40];
    __shared__ short sBh[64 * 40],  sBm[64 * 40],  sBl[64 * 40];
    const int tid = threadIdx.x;
    // XCD-aware remap: XCD cx owns 16 consecutive m-tiles x all 16 n-tiles
    const int lin = blockIdx.x;
    const int cx = lin & 7, j = lin >> 3;
    const int m0 = (cx * 16 + (j >> 4)) * 128;
    const int n0 = (j & 15) * 64;
    const int b = m0 >> 11, t0 = m0 & 2047;
    const float* xb = x + (size_t)b * CIN * TT + 2 * t0;

    const int aw = tid >> 6, p = tid & 63;          // A-load mapping
    const int brow = tid >> 2, bq = tid & 3;        // B-load mapping
    const int ln = tid & 15, quad = (tid >> 4) & 3;
    const int r0 = (aw >> 1) * 64, c0 = (aw & 1) * 32;

    f32x4 acc[4][2], sums[4][2];
#pragma unroll
    for (int r = 0; r < 4; ++r)
#pragma unroll
        for (int c = 0; c < 2; ++c) { acc[r][c] = 0.f; sums[r][c] = 0.f; }

    float4 av[4];
    uint4 bh0, bm0, bl0;
#pragma unroll
    for (int r = 0; r < 4; ++r) av[r] = *(const float4*)(xb + (size_t)(4 * r + aw) * TT + 4 * p);
    {
        const size_t o = (size_t)(n0 + brow) * 2048 + bq * 8;
        bh0 = *(const uint4*)&wh[o]; bm0 = *(const uint4*)&wm[o]; bl0 = *(const uint4*)&wl[o];
    }

    for (int it = 0; it < 64; ++it) {
        __syncthreads();
#pragma unroll
        for (int r = 0; r < 4; ++r) {
            const int ii = r * 4 + aw;              // channel in tile, k_loc=2*ii+s
            const int q = ii >> 2, off = (2 * ii) & 7;
            const int a0 = aswz(2 * p, q) + off;
            const int a1 = aswz(2 * p + 1, q) + off;
            float4 v = av[r];
            short hx, mx, lx, hy, my, ly;
            split3(v.x, hx, mx, lx); split3(v.y, hy, my, ly);
            *(unsigned*)&sAh[a0] = pk(hx, hy);
            *(unsigned*)&sAm[a0] = pk(mx, my);
            *(unsigned*)&sAl[a0] = pk(lx, ly);
            split3(v.z, hx, mx, lx); split3(v.w, hy, my, ly);
            *(unsigned*)&sAh[a1] = pk(hx, hy);
            *(unsigned*)&sAm[a1] = pk(mx, my);
            *(unsigned*)&sAl[a1] = pk(lx, ly);
        }
        {
            const int w0 = brow * 40 + bq * 8;
            *(uint4*)&sBh[w0] = bh0; *(uint4*)&sBm[w0] = bm0; *(uint4*)&sBl[w0] = bl0;
        }
        __syncthreads();
        if (it + 1 < 64) {
            const int i0 = (it + 1) * 16, k0 = (it + 1) * 32;
#pragma unroll
            for (int r = 0; r < 4; ++r)
                av[r] = *(const float4*)(xb + (size_t)(i0 + 4 * r + aw) * TT + 4 * p);
            const size_t o = (size_t)(n0 + brow) * 2048 + k0 + bq * 8;
            bh0 = *(const uint4*)&wh[o]; bm0 = *(const uint4*)&wm[o]; bl0 = *(const uint4*)&wl[o];
        }
        s16x8 fah[4], fam[4], fal[4];
#pragma unroll
        for (int r = 0; r < 4; ++r) {
            const int base = aswz(r0 + r * 16 + ln, quad);
            fah[r] = *(const s16x8*)&sAh[base];
            fam[r] = *(const s16x8*)&sAm[base];
            fal[r] = *(const s16x8*)&sAl[base];
        }
#pragma unroll
        for (int c = 0; c < 2; ++c) {
            const int bb = (c0 + c * 16 + ln) * 40 + quad * 8;
            s16x8 fbh = *(const s16x8*)&sBh[bb];
            s16x8 fbm = *(const s16x8*)&sBm[bb];
            s16x8 fbl = *(const s16x8*)&sBl[bb];
#pragma unroll
            for (int r = 0; r < 4; ++r) {
                acc[r][c] = __builtin_amdgcn_mfma_f32_16x16x32_bf16(fah[r], fbh, acc[r][c], 0, 0, 0);
                acc[r][c] = __builtin_amdgcn_mfma_f32_16x16x32_bf16(fah[r], fbm, acc[r][c], 0, 0, 0);
                acc[r][c] = __builtin_amdgcn_mfma_f32_16x16x32_bf16(fam[r], fbh, acc[r][c], 0, 0, 0);
                acc[r][c] = __builtin_amdgcn_mfma_f32_16x16x32_bf16(fah[r], fbl, acc[r][c], 0, 0, 0);
                acc[r][c] = __builtin_amdgcn_mfma_f32_16x16x32_bf16(fam[r], fbm, acc[r][c], 0, 0, 0);
                acc[r][c] = __builtin_amdgcn_mfma_f32_16x16x32_bf16(fal[r], fbh, acc[r][c], 0, 0, 0);
            }
        }
        if (it & 1) {   // chunk flush (K=64)
#pragma unroll
            for (int r = 0; r < 4; ++r)
#pragma unroll
                for (int c = 0; c < 2; ++c) { sums[r][c] += acc[r][c]; acc[r][c] = 0.f; }
        }
    }
#pragma unroll
    for (int c = 0; c < 2; ++c) {
        const int n = n0 + c0 + c * 16 + ln;
        const float bv = bias[n];
#pragma unroll
        for (int r = 0; r < 4; ++r)
#pragma unroll
            for (int g = 0; g < 4; ++g) {
                const int m = m0 + r0 + r * 16 + quad * 4 + g;
                const float v = sums[r][c][g] + bv;
                const size_t o = (size_t)m * DVQ + n;
                xt[o] = v;
                short h = f2bf(v);
                xth[o] = h;
                xtl[o] = f2bf(v - bf2f(h));
            }
    }
}

// ====== distance GEMM (2-plane planes from conv) + fused exact top-2 =======
// One 128(M)x128(N) tile per block; 16 n-strips merged in k_pick.
__global__ __launch_bounds__(256, 2) void k_dot(const short* __restrict__ xth,
                                                const short* __restrict__ xtl,
                                                const short* __restrict__ cbh,
                                                const short* __restrict__ cbl,
                                                const float* __restrict__ c32,
                                                float4* __restrict__ pb) {
    __shared__ __align__(16) short sAh[128 * 40], sAl[128 * 40], sBh[128 * 40], sBl[128 * 40];
    const int tid = threadIdx.x;
    const int n0 = blockIdx.x * 128, m0 = blockIdx.y * 128;
    const int ar = tid >> 2, q = tid & 3, kk = q * 8;
    const int ln = tid & 15, quad = (tid >> 4) & 3, wv = tid >> 6;
    const int r0 = (wv >> 1) * 64, c0 = (wv & 1) * 64;

    f32x4 acc[4][4];
#pragma unroll
    for (int r = 0; r < 4; ++r)
#pragma unroll
        for (int c = 0; c < 4; ++c) acc[r][c] = 0.f;

    uint4 a0 = *(const uint4*)&xth[(size_t)(m0 + ar) * 1024 + kk];
    uint4 a1 = *(const uint4*)&xth[(size_t)(m0 + 64 + ar) * 1024 + kk];
    uint4 a2 = *(const uint4*)&xtl[(size_t)(m0 + ar) * 1024 + kk];
    uint4 a3 = *(const uint4*)&xtl[(size_t)(m0 + 64 + ar) * 1024 + kk];
    uint4 b0 = *(const uint4*)&cbh[(size_t)(n0 + ar) * 1024 + kk];
    uint4 b1 = *(const uint4*)&cbh[(size_t)(n0 + 64 + ar) * 1024 + kk];
    uint4 b2 = *(const uint4*)&cbl[(size_t)(n0 + ar) * 1024 + kk];
    uint4 b3 = *(const uint4*)&cbl[(size_t)(n0 + 64 + ar) * 1024 + kk];

    for (int it = 0; it < 32; ++it) {
        __syncthreads();
        *(uint4*)&sAh[aswz(ar, q)] = a0;
        *(uint4*)&sAh[aswz(64 + ar, q)] = a1;
        *(uint4*)&sAl[aswz(ar, q)] = a2;
        *(uint4*)&sAl[aswz(64 + ar, q)] = a3;
        {
            const int w0 = ar * 40 + kk, w1 = (64 + ar) * 40 + kk;
            *(uint4*)&sBh[w0] = b0; *(uint4*)&sBh[w1] = b1;
            *(uint4*)&sBl[w0] = b2; *(uint4*)&sBl[w1] = b3;
        }
        __syncthreads();
        if (it + 1 < 32) {
            const int k0 = (it + 1) * 32;
            a0 = *(const uint4*)&xth[(size_t)(m0 + ar) * 1024 + k0 + kk];
            a1 = *(const uint4*)&xth[(size_t)(m0 + 64 + ar) * 1024 + k0 + kk];
            a2 = *(const uint4*)&xtl[(size_t)(m0 + ar) * 1024 + k0 + kk];
            a3 = *(const uint4*)&xtl[(size_t)(m0 + 64 + ar) * 1024 + k0 + kk];
            b0 = *(const uint4*)&cbh[(size_t)(n0 + ar) * 1024 + k0 + kk];
            b1 = *(const uint4*)&cbh[(size_t)(n0 + 64 + ar) * 1024 + k0 + kk];
            b2 = *(const uint4*)&cbl[(size_t)(n0 + ar) * 1024 + k0 + kk];
            b3 = *(const uint4*)&cbl[(size_t)(n0 + 64 + ar) * 1024 + k0 + kk];
        }
        s16x8 fah[4], fal[4];
#pragma unroll
        for (int r = 0; r < 4; ++r) {
            const int base = aswz(r0 + r * 16 + ln, quad);
            fah[r] = *(const s16x8*)&sAh[base];
            fal[r] = *(const s16x8*)&sAl[base];
        }
#pragma unroll
        for (int c = 0; c < 4; ++c) {
            const int bb = (c0 + c * 16 + ln) * 40 + quad * 8;
            s16x8 fbh = *(const s16x8*)&sBh[bb];
            s16x8 fbl = *(const s16x8*)&sBl[bb];
#pragma unroll
            for (int r = 0; r < 4; ++r) {
                acc[r][c] = __builtin_amdgcn_mfma_f32_16x16x32_bf16(fah[r], fbh, acc[r][c], 0, 0, 0);
                acc[r][c] = __builtin_amdgcn_mfma_f32_16x16x32_bf16(fah[r], fbl, acc[r][c], 0, 0, 0);
                acc[r][c] = __builtin_amdgcn_mfma_f32_16x16x32_bf16(fal[r], fbh, acc[r][c], 0, 0, 0);
            }
        }
    }
    // per-thread top-2 (ascending n per row; strict < keeps first occurrence)
    float tb1[16], tb2[16]; int tk1[16], tk2[16];
#pragma unroll
    for (int i = 0; i < 16; ++i) { tb1[i] = INFINITY; tb2[i] = INFINITY; tk1[i] = 0; tk2[i] = 0; }
#pragma unroll
    for (int c = 0; c < 4; ++c) {
        const int n = n0 + c0 + c * 16 + ln;
        const float cn = c32[n];
#pragma unroll
        for (int r = 0; r < 4; ++r)
#pragma unroll
            for (int g = 0; g < 4; ++g) {
                const float s = cn - 2.0f * acc[r][c][g];
                const int i = r * 4 + g;
                if (s < tb1[i]) { tb2[i] = tb1[i]; tk2[i] = tk1[i]; tb1[i] = s; tk1[i] = n; }
                else if (s < tb2[i]) { tb2[i] = s; tk2[i] = n; }
            }
    }
    // lossless top-2 butterfly across the 16 ln-lanes
#pragma unroll
    for (int off = 1; off < 16; off <<= 1) {
#pragma unroll
        for (int i = 0; i < 16; ++i) {
            float o1 = __shfl_xor(tb1[i], off); int ok1 = __shfl_xor(tk1[i], off);
            float o2 = __shfl_xor(tb2[i], off); int ok2 = __shfl_xor(tk2[i], off);
            merge2(tb1[i], tk1[i], tb2[i], tk2[i], o1, ok1, o2, ok2);
        }
    }
    __syncthreads();
    float4* part = (float4*)sAh;   // 4 KB overlay
    if (ln == 0) {
#pragma unroll
        for (int i = 0; i < 16; ++i) {
            const int lr = (i >> 2) * 16 + quad * 4 + (i & 3);
            float4 v; v.x = tb1[i]; v.y = tb2[i];
            v.z = __int_as_float(tk1[i]); v.w = __int_as_float(tk2[i]);
            part[wv * 64 + lr] = v;
        }
    }
    __syncthreads();
    if (tid < 128) {
        const int row = tid, h = row >> 6, lr = row & 63;
        float4 A = part[(2 * h) * 64 + lr];
        float4 B = part[(2 * h + 1) * 64 + lr];
        float b1v = A.x, b2v = A.y; int k1 = __float_as_int(A.z), k2 = __float_as_int(A.w);
        merge2(b1v, k1, b2v, k2, B.x, __float_as_int(B.z), B.y, __float_as_int(B.w));
        float4 o; o.x = b1v; o.y = b2v; o.z = __int_as_float(k1); o.w = __int_as_float(k2);
        pb[(size_t)blockIdx.x * MM + m0 + row] = o;
    }
}

// ============ merge 16 strips + exact f64 rescore of top-2 =================
__global__ __launch_bounds__(256) void k_pick(const float4* __restrict__ pb,
                                              const double* __restrict__ c64,
                                              const float* __restrict__ xt,
                                              const float* __restrict__ cb,
                                              int* __restrict__ idxbuf,
                                              float* __restrict__ idx_out) {
    const int wv = threadIdx.x >> 6, lane = threadIdx.x & 63;
    const int m = blockIdx.x * 4 + wv;
    float4 P = pb[m];
    float b1 = P.x, b2 = P.y; int k1 = __float_as_int(P.z), k2 = __float_as_int(P.w);
#pragma unroll
    for (int s = 1; s < 16; ++s) {
        float4 Q = pb[(size_t)s * MM + m];
        merge2(b1, k1, b2, k2, Q.x, __float_as_int(Q.z), Q.y, __float_as_int(Q.w));
    }
    const float* xr = xt + (size_t)m * DVQ;
    const float* c1 = cb + (size_t)k1 * DVQ;
    const float* c2 = cb + (size_t)k2 * DVQ;
    double e1 = 0.0, e2 = 0.0;
    for (int j = 0; j < DVQ / 64; ++j) {
        const int d = j * 64 + lane;
        const double xv = xr[d];
        e1 += xv * (double)c1[d]; e2 += xv * (double)c2[d];
    }
    for (int off = 32; off > 0; off >>= 1) { e1 += __shfl_xor(e1, off); e2 += __shfl_xor(e2, off); }
    if (lane == 0) {
        const double s1 = c64[k1] - 2.0 * e1;
        const double s2 = c64[k2] - 2.0 * e2;
        const int kf = (s2 < s1 || (s2 == s1 && k2 < k1)) ? k2 : k1;
        idxbuf[m] = kf;
        idx_out[m] = (float)kf;
    }
}

// ================================= loss ====================================
__global__ __launch_bounds__(256) void k_losspart(const float* __restrict__ xt,
                                                  const float* __restrict__ cb,
                                                  const int* __restrict__ idxbuf,
                                                  float* __restrict__ partials) {
    __shared__ float red[256];
    const int m = blockIdx.x;
    const int row = idxbuf[m];
    float4 a = ((const float4*)(xt + (size_t)m * DVQ))[threadIdx.x];
    float4 c = ((const float4*)(cb + (size_t)row * DVQ))[threadIdx.x];
    const float dx = a.x - c.x, dy = a.y - c.y, dz = a.z - c.z, dw = a.w - c.w;
    red[threadIdx.x] = dx * dx + dy * dy + dz * dz + dw * dw;
    __syncthreads();
    for (int o = 128; o > 0; o >>= 1) {
        if (threadIdx.x < o) red[threadIdx.x] += red[threadIdx.x + o];
        __syncthreads();
    }
    if (threadIdx.x == 0) partials[m] = red[0];
}

__global__ __launch_bounds__(256) void k_lossfinal(const float* __restrict__ partials,
                                                   float* __restrict__ loss_out) {
    __shared__ float red[256];
    float s = 0.0f;
    for (int i = threadIdx.x; i < MM; i += 256) s += partials[i];
    red[threadIdx.x] = s;
    __syncthreads();
    for (int o = 128; o > 0; o >>= 1) {
        if (threadIdx.x < o) red[threadIdx.x] += red[threadIdx.x + o];
        __syncthreads();
    }
    if (threadIdx.x == 0) loss_out[0] = red[0] / (float)((size_t)MM * DVQ);
}

// ============== out projection (gathered codebook, 2-plane) ================
__global__ __launch_bounds__(256, 2) void k_out(const int* __restrict__ idxbuf,
                                                const short* __restrict__ ch,
                                                const short* __restrict__ cl,
                                                const short* __restrict__ wh,
                                                const short* __restrict__ wl,
                                                const float* __restrict__ bias,
                                                const float* __restrict__ xm,
                                                float* __restrict__ outp) {
    __shared__ short sAh[128 * 40], sAl[128 * 40], sBh[128 * 40], sBl[128 * 40];
    __shared__ int rows_s[128];
    const int tid = threadIdx.x;
    const int m0 = blockIdx.y * 128, n0 = blockIdx.x * 128;
    if (tid < 128) rows_s[tid] = idxbuf[m0 + tid];
    __syncthreads();
    const int ar = tid >> 2, q = tid & 3, kk = q * 8;
    const int ln = tid & 15, quad = (tid >> 4) & 3, wv = tid >> 6;
    const int r0 = (wv >> 1) * 64, c0 = (wv & 1) * 64;
    const size_t ra0 = (size_t)rows_s[ar] * 1024, ra1 = (size_t)rows_s[64 + ar] * 1024;

    f32x4 acc[4][4];
#pragma unroll
    for (int r = 0; r < 4; ++r)
#pragma unroll
        for (int c = 0; c < 4; ++c) acc[r][c] = 0.f;

    uint4 a0 = *(const uint4*)&ch[ra0 + kk];
    uint4 a1 = *(const uint4*)&ch[ra1 + kk];
    uint4 a2 = *(const uint4*)&cl[ra0 + kk];
    uint4 a3 = *(const uint4*)&cl[ra1 + kk];
    uint4 b0 = *(const uint4*)&wh[(size_t)(n0 + ar) * 1024 + kk];
    uint4 b1 = *(const uint4*)&wh[(size_t)(n0 + 64 + ar) * 1024 + kk];
    uint4 b2 = *(const uint4*)&wl[(size_t)(n0 + ar) * 1024 + kk];
    uint4 b3 = *(const uint4*)&wl[(size_t)(n0 + 64 + ar) * 1024 + kk];

    for (int it = 0; it < 32; ++it) {
        __syncthreads();
        *(uint4*)&sAh[aswz(ar, q)] = a0;
        *(uint4*)&sAh[aswz(64 + ar, q)] = a1;
        *(uint4*)&sAl[aswz(ar, q)] = a2;
        *(uint4*)&sAl[aswz(64 + ar, q)] = a3;
        {
            const int w0 = ar * 40 + kk, w1 = (64 + ar) * 40 + kk;
            *(uint4*)&sBh[w0] = b0; *(uint4*)&sBh[w1] = b1;
            *(uint4*)&sBl[w0] = b2; *(uint4*)&sBl[w1] = b3;
        }
        __syncthreads();
        if (it + 1 < 32) {
            const int k0 = (it + 1) * 32;
            a0 = *(const uint4*)&ch[ra0 + k0 + kk];
            a1 = *(const uint4*)&ch[ra1 + k0 + kk];
            a2 = *(const uint4*)&cl[ra0 + k0 + kk];
            a3 = *(const uint4*)&cl[ra1 + k0 + kk];
            b0 = *(const uint4*)&wh[(size_t)(n0 + ar) * 1024 + k0 + kk];
            b1 = *(const uint4*)&wh[(size_t)(n0 + 64 + ar) * 1024 + k0 + kk];
            b2 = *(const uint4*)&wl[(size_t)(n0 + ar) * 1024 + k0 + kk];
            b3 = *(const uint4*)&wl[(size_t)(n0 + 64 + ar) * 1024 + k0 + kk];
        }
        s16x8 fah[4], fal[4];
#pragma unroll
        for (int r = 0; r < 4; ++r) {
            const int base = aswz(r0 + r * 16 + ln, quad);
            fah[r] = *(const s16x8*)&sAh[base];
            fal[r] = *(const s16x8*)&sAl[base];
        }
#pragma unroll
        for (int c = 0; c < 4; ++c) {
            const int bb = (c0 + c * 16 + ln) * 40 + quad * 8;
            s16x8 fbh = *(const s16x8*)&sBh[bb];
            s16x8 fbl = *(const s16x8*)&sBl[bb];
#pragma unroll
            for (int r = 0; r < 4; ++r) {
                acc[r][c] = __builtin_amdgcn_mfma_f32_16x16x32_bf16(fah[r], fbh, acc[r][c], 0, 0, 0);
                acc[r][c] = __builtin_amdgcn_mfma_f32_16x16x32_bf16(fah[r], fbl, acc[r][c], 0, 0, 0);
                acc[r][c] = __builtin_amdgcn_mfma_f32_16x16x32_bf16(fal[r], fbh, acc[r][c], 0, 0, 0);
            }
        }
    }
#pragma unroll
    for (int c = 0; c < 4; ++c) {
        const int n = n0 + c0 + c * 16 + ln;
        const float bv = bias[n];
#pragma unroll
        for (int r = 0; r < 4; ++r)
#pragma unroll
            for (int g = 0; g < 4; ++g) {
                const int m = m0 + r0 + r * 16 + quad * 4 + g;
                const int b = m >> 11, t = m & 2047;
                const float mk0 = xm[(size_t)b * TT + 2 * t];
                const float mk1 = xm[(size_t)b * TT + 2 * t + 1];
                const float v = acc[r][c][g] + bv;
                float2 o2; o2.x = v * mk0; o2.y = v * mk1;
                *(float2*)&outp[((size_t)b * CIN + n) * TT + 2 * t] = o2;
            }
    }
}

// ================================ launch ===================================
extern "C" void kernel_launch(void* const* d_in, const int* in_sizes, int n_in,
                              void* d_out, int out_size, void* d_ws, size_t ws_size,
                              hipStream_t stream) {
    const float* x  = (const float*)d_in[0];
    const float* xm = (const float*)d_in[1];
    const float* wi = (const float*)d_in[2];
    const float* bi = (const float*)d_in[3];
    const float* cb = (const float*)d_in[4];
    const float* wo = (const float*)d_in[5];
    const float* bo = (const float*)d_in[6];

    float* outp     = (float*)d_out;
    float* idx_out  = outp + (size_t)NB * CIN * TT;   // offset 33,554,432 floats
    float* loss_out = idx_out + MM;
    // scratch inside d_out's 128 MB out-region (dead before k_out rewrites it):
    // xt f32 (64 MB) + xthi (32 MB) + xtlo (32 MB) = exactly 128 MB.
    float* xt  = outp;
    short* xth = (short*)(outp + 16777216);
    short* xtl = xth + 16777216;

    char* p = (char*)d_ws;   // ~28.2 MB total (R1 proved >=65 MB safe)
    short* wih = (short*)p; p += (size_t)CIN * 2048 * 2;
    short* wim = (short*)p; p += (size_t)CIN * 2048 * 2;
    short* wil = (short*)p; p += (size_t)CIN * 2048 * 2;
    short* cbh = (short*)p; p += (size_t)KC * DVQ * 2;
    short* cbl = (short*)p; p += (size_t)KC * DVQ * 2;
    short* woh = (short*)p; p += (size_t)CIN * DVQ * 2;
    short* wol = (short*)p; p += (size_t)CIN * DVQ * 2;
    float*  c32 = (float*)p;  p += KC * sizeof(float);
    double* c64 = (double*)p; p += KC * sizeof(double);
    float4* pb  = (float4*)p; p += (size_t)16 * MM * sizeof(float4);
    float* partials = (float*)p; p += MM * sizeof(float);
    int*   idxbuf   = (int*)p;

    dim3 blk(256);
    k_split3<<<dim3(2048), blk, 0, stream>>>(wi, wih, wim, wil, CIN * 2048 / 4);
    k_split2<<<dim3(2048), blk, 0, stream>>>(cb, cbh, cbl, KC * DVQ / 4);
    k_split2<<<dim3(1024), blk, 0, stream>>>(wo, woh, wol, CIN * DVQ / 4);
    k_cnorm <<<dim3(KC),   blk, 0, stream>>>(cb, c32, c64);
    k_conv  <<<dim3(2048), blk, 0, stream>>>(x, wih, wim, wil, bi, xt, xth, xtl);
    k_dot   <<<dim3(16, 128), blk, 0, stream>>>(xth, xtl, cbh, cbl, c32, pb);
    k_pick  <<<dim3(MM / 4), blk, 0, stream>>>(pb, c64, xt, cb, idxbuf, idx_out);
    k_losspart<<<dim3(MM), blk, 0, stream>>>(xt, cb, idxbuf, partials);
    k_lossfinal<<<1, blk, 0, stream>>>(partials, loss_out);
    k_out   <<<dim3(8, 128), blk, 0, stream>>>(idxbuf, cbh, cbl, woh, wol, bo, xm, outp);
}